// Round 3
// baseline (94.140 us; speedup 1.0000x reference)
//
#include <hip/hip_runtime.h>
#include <math.h>

// Fuzzy LeNet-5, Yager p=1 == Lukasiewicz: T(a,b)=max(0,a+b-1).
// Fuzzy conv == max-plus conv: out = relu(max_{c,kh,kw}(x+w) - 1).
// maxpool2 folds into the conv via dilated 6x6 weights:
//   W'[uy][ux] = max_{dy,dx in {0,1}, uy-dy,ux-dx in [0,5)} w[uy-dy][ux-dx]
//
// R16: ZERO LDS ATOMICS. Evidence: R14 (+50% atomic lane-ops, deeper
// same-address chains) cost +16us; R15 (barriers/VALU reshaped, atomics
// untouched) was neutral. So the critical resource is LDS atomic RMW
// serialization (conv1: 7056 lane-ops, 6 contributors/address; conv2:
// 4800 lane-ops, 12 contributors/address). Fix: keep R13 per-thread conv
// bodies EXACTLY, but re-index tasks so all contributors to an output
// share a wave: conv1 = 8-lane groups (c 0..3 dummy-padded x h), conv2 =
// 16-lane groups (c 0..7 dummy-padded x h). Combine with DPP max-trees
// (quad_perm xor1/xor2 + row_shl:4/8 -- VALU pipe), lane 0 of each group
// does ONE plain ds_write per output. Also deletes phase-A zeroing of
// s_a1/s_a2 (every output now written exactly once). Phases E/F shfl_xor
// (ds_swizzle, LDS pipe) -> same DPP trees. s_in channel stride padded
// 1088->1096 so c-in-lane layout spreads LDS banks (+8/c).
// w3/wd prefetch placement preserved (prefetch-only waves still skip conv
// bodies via execz and issue loads immediately -- R14's other lesson).

#define NT 1024
#define ROWS 34                 // padded image row stride
#define PLANEF 1096             // padded channel stride (32*34 + 8)

// DPP lane-combine helpers. row_shr:1 gives lane i <- lane i-1 (GPUOpen
// cross-lane doc), so row_shl:N gives lane i <- lane i+N.
#define QX1  0xB1   // quad_perm [1,0,3,2] : lane ^= 1
#define QX2  0x4E   // quad_perm [2,3,0,1] : lane ^= 2
#define SHL4 0x104  // row_shl:4 : lane i <- lane i+4 (valid where needed)
#define SHL8 0x108  // row_shl:8 : lane i <- lane i+8

template<int CTRL>
__device__ __forceinline__ float dppmax(float v) {
    int p = __builtin_amdgcn_update_dpp(0, __float_as_int(v), CTRL, 0xF, 0xF, true);
    return fmaxf(v, __int_as_float(p));   // invalid lanes read 0; values >= 0
}
template<int CTRL>
__device__ __forceinline__ float dppadd(float v) {
    int p = __builtin_amdgcn_update_dpp(0, __float_as_int(v), CTRL, 0xF, 0xF, true);
    return v + __int_as_float(p);         // invalid lanes read 0: safe for sum
}

// LDS-only workgroup barrier: waits LDS ops, leaves global loads in flight.
__device__ __forceinline__ void bar_lds() {
    asm volatile("s_waitcnt lgkmcnt(0)" ::: "memory");
    __builtin_amdgcn_s_barrier();
    asm volatile("" ::: "memory");
}

__device__ __forceinline__ void dilate_row(const float* __restrict__ raw,
                                           int r, float* __restrict__ dst) {
    // dst[0..5] = max over kh in {r-1,r} cap [0,4], kw in {col-1,col} cap [0,4]
    const int rA = (r > 0) ? r - 1 : 0;
    const int rB = (r < 5) ? r : 4;
    float t0 = fmaxf(raw[rA * 5 + 0], raw[rB * 5 + 0]);
    float t1 = fmaxf(raw[rA * 5 + 1], raw[rB * 5 + 1]);
    float t2 = fmaxf(raw[rA * 5 + 2], raw[rB * 5 + 2]);
    float t3 = fmaxf(raw[rA * 5 + 3], raw[rB * 5 + 3]);
    float t4 = fmaxf(raw[rA * 5 + 4], raw[rB * 5 + 4]);
    float2* d = (float2*)dst;
    d[0] = make_float2(t0, fmaxf(t0, t1));
    d[1] = make_float2(fmaxf(t1, t2), fmaxf(t2, t3));
    d[2] = make_float2(fmaxf(t3, t4), t4);
}

__global__ __launch_bounds__(NT) void fused_lenet(
    const float* __restrict__ x,   // [B,3,32,32]
    const float* __restrict__ w1,  // [6,3,5,5]
    const float* __restrict__ w2,  // [16,6,5,5]
    const float* __restrict__ w3,  // [120,16,5,5]
    const float* __restrict__ wd,  // [120,84]
    const float* __restrict__ wf,  // [84,10]
    const float* __restrict__ bfv, // [10]
    float* __restrict__ out)       // [B,10]
{
    const int img = blockIdx.x;
    const int tid = threadIdx.x;

    __shared__ __align__(16) float s_in[3 * PLANEF];   // 13152 B
    __shared__ float s_w1d[648];               // [oc][c][uy][6]
    __shared__ float s_w2d[3456];              // [oc][c][uy][6]
    __shared__ __align__(16) float s_wf[852];  // wf[840] + bf[10]
    __shared__ __align__(16) float s_a1f[1176];// conv1 out (relu'd)
    __shared__ __align__(16) float s_a2f[400]; // conv2 out (relu'd)
    __shared__ float s_a3[120];
    __shared__ float s_a4[84];

    float4 w3p[13];   // filled after conv1 body, consumed in phase E

    // ---- Phase A: stage image + wf/bf + dilate w1 AND w2
    //      (no accumulator zeroing needed anymore: every a1/a2 slot is
    //       written exactly once by its owning lane-group)
    {
        const float2* src = (const float2*)(x + img * 3072);
        for (int i = tid; i < 1536; i += NT) {
            const int c = i >> 9, rem = i & 511, r = rem >> 4, col2 = rem & 15;
            ((float2*)s_in)[c * (PLANEF / 2) + r * (ROWS / 2) + col2] = src[i];
        }
        if (tid < 420) ((float2*)s_wf)[tid] = ((const float2*)wf)[tid];
        if (tid >= 428 && tid < 438) s_wf[840 + tid - 428] = bfv[tid - 428];
        if (tid >= 320 && tid < 428) {          // w1 dilation: 108 row-tasks
            const int e = tid - 320;
            const int occ = e / 6, r = e - occ * 6;   // occ = oc*3+c
            dilate_row(w1 + occ * 25, r, s_w1d + occ * 36 + r * 6);
        }
        if (tid >= 448) {                       // w2 dilation: 576 row-tasks
            const int e = tid - 448;
            const int occ = e / 6, r = e - occ * 6;   // occ = oc*6+c
            dilate_row(w2 + occ * 25, r, s_w2d + occ * 36 + r * 6);
        }
    }
    bar_lds();

    // ---- Phase C: conv1; 448 threads = 56 groups x 8 lanes.
    //      Lane l = cc*2+h, cc in 0..3 (cc==3 duplicates c=2), h in {0,1}.
    //      Group g = (ocg,py,s). Per-thread body identical to R13 (3 oc,
    //      3 uy, 7 px). Partials combined over (c,h) via DPP tree; lane 0
    //      of each group writes the relu'd output. Zero atomics.
    if (tid < 448) {
        const int l = tid & 7;
        const int h = l & 1;
        const int cc = l >> 1;
        const int c = (cc < 3) ? cc : 2;        // dummy lanes repeat c=2
        const int g = tid >> 3;                 // 0..55
        const int ocg = g / 28;
        const int rem = g - ocg * 28;
        const int py = rem >> 1;
        const int s = rem & 1;
        float acc[3][7];
        #pragma unroll
        for (int o = 0; o < 3; ++o)
            #pragma unroll
            for (int j = 0; j < 7; ++j) acc[o][j] = -1e30f;
        const float* xbase = s_in + c * PLANEF + (2 * py + 3 * h) * ROWS + 14 * s;
        #pragma unroll
        for (int u = 0; u < 3; ++u) {
            float xv[18];
            #pragma unroll
            for (int i2 = 0; i2 < 9; ++i2)
                ((float2*)xv)[i2] = ((const float2*)(xbase + u * ROWS))[i2];
            #pragma unroll
            for (int o = 0; o < 3; ++o) {
                const float* wbase =
                    s_w1d + ((ocg * 3 + o) * 3 + c) * 36 + h * 18 + u * 6;
                float wv[6];
                #pragma unroll
                for (int i2 = 0; i2 < 3; ++i2)
                    ((float2*)wv)[i2] = ((const float2*)wbase)[i2];
                #pragma unroll
                for (int j = 0; j < 7; ++j) {
                    const float t0 = xv[2 * j + 0] + wv[0];
                    const float t1 = xv[2 * j + 1] + wv[1];
                    const float t2 = xv[2 * j + 2] + wv[2];
                    const float t3 = xv[2 * j + 3] + wv[3];
                    const float t4 = xv[2 * j + 4] + wv[4];
                    const float t5 = xv[2 * j + 5] + wv[5];
                    const float m1 = fmaxf(fmaxf(t0, t1), t2);   // v_max3
                    const float m2 = fmaxf(fmaxf(t3, t4), t5);   // v_max3
                    acc[o][j] = fmaxf(acc[o][j], fmaxf(m1, m2)); // v_max3
                }
            }
        }
        #pragma unroll
        for (int o = 0; o < 3; ++o) {
            const int obase = (ocg * 3 + o) * 196 + py * 14 + 7 * s;
            #pragma unroll
            for (int j = 0; j < 7; ++j) {
                float v = dppmax<QX1>(acc[o][j]);   // combine h
                v = dppmax<QX2>(v);                 // combine c pairs
                v = dppmax<SHL4>(v);                // combine quads (lane 0,8)
                if (l == 0) s_a1f[obase + j] = fmaxf(v - 1.0f, 0.0f);
            }
        }
    }
    // prefetch w3 into registers (in flight through conv2 + barriers, used E)
    if (tid < 960) {
        const int o = tid >> 3, q = tid & 7;
        const float4* wv = (const float4*)(w3 + o * 400);
        #pragma unroll
        for (int i = 0; i < 13; ++i) {
            int l2 = q + 8 * i; if (l2 > 99) l2 = 99;
            w3p[i] = wv[l2];
        }
    }
    bar_lds();

    // ---- Phase D: conv2; 320 threads = 20 groups x 16 lanes.
    //      Lane l = cc*2+h, cc in 0..7 (6,7 duplicate c=5). Group g =
    //      (ocq,py). Body identical to R13 (4 oc, 3 uy, 5 px). DPP tree
    //      over 16 lanes; lane 0 writes. Zero atomics.
    if (tid < 320) {
        const int l = tid & 15;
        const int h = l & 1;
        const int cc = l >> 1;
        const int c = (cc < 6) ? cc : 5;        // dummy lanes repeat c=5
        const int g = tid >> 4;                 // 0..19
        const int ocq = g / 5;
        const int py = g - ocq * 5;
        float acc[4][5];
        #pragma unroll
        for (int o = 0; o < 4; ++o)
            #pragma unroll
            for (int j = 0; j < 5; ++j) acc[o][j] = -1e30f;
        const float* xbase = s_a1f + c * 196 + (2 * py + 3 * h) * 14;
        #pragma unroll
        for (int u = 0; u < 3; ++u) {
            float xv[14];
            #pragma unroll
            for (int i2 = 0; i2 < 7; ++i2)
                ((float2*)xv)[i2] = ((const float2*)(xbase + u * 14))[i2];
            #pragma unroll
            for (int o = 0; o < 4; ++o) {
                const float* wbase =
                    s_w2d + ((ocq * 4 + o) * 6 + c) * 36 + h * 18 + u * 6;
                float wv[6];
                #pragma unroll
                for (int i2 = 0; i2 < 3; ++i2)
                    ((float2*)wv)[i2] = ((const float2*)wbase)[i2];
                #pragma unroll
                for (int j = 0; j < 5; ++j) {
                    const float t0 = xv[2 * j + 0] + wv[0];
                    const float t1 = xv[2 * j + 1] + wv[1];
                    const float t2 = xv[2 * j + 2] + wv[2];
                    const float t3 = xv[2 * j + 3] + wv[3];
                    const float t4 = xv[2 * j + 4] + wv[4];
                    const float t5 = xv[2 * j + 5] + wv[5];
                    const float m1 = fmaxf(fmaxf(t0, t1), t2);   // v_max3
                    const float m2 = fmaxf(fmaxf(t3, t4), t5);   // v_max3
                    acc[o][j] = fmaxf(acc[o][j], fmaxf(m1, m2)); // v_max3
                }
            }
        }
        #pragma unroll
        for (int o = 0; o < 4; ++o) {
            const int obase = (ocq * 4 + o) * 25 + py * 5;
            #pragma unroll
            for (int j = 0; j < 5; ++j) {
                float v = dppmax<QX1>(acc[o][j]);   // h
                v = dppmax<QX2>(v);                 // c pairs
                v = dppmax<SHL4>(v);                // quads (lanes 0,8 valid)
                v = dppmax<SHL8>(v);                // halves (lane 0 valid)
                if (l == 0) s_a2f[obase + j] = fmaxf(v - 1.0f, 0.0f);
            }
        }
    }
    // prefetch wd for the dense phase (in flight during E)
    float wdp[15];
    if (tid < 672) {
        const int o = tid >> 3, q = tid & 7;
        #pragma unroll
        for (int i = 0; i < 15; ++i)
            wdp[i] = wd[(q * 15 + i) * 84 + o];
    }
    bar_lds();

    // ---- Phase E: L3 [16,5,5]->[120]; 8 threads/output, prefetched w3;
    //      8-lane DPP max-tree (result on q==0 lanes = lane%8==0)
    if (tid < 960) {
        const int o = tid >> 3, q = tid & 7;
        const float4* av = (const float4*)s_a2f;
        float m = -1e30f;
        #pragma unroll
        for (int i = 0; i < 13; ++i) {
            int l2 = q + 8 * i; if (l2 > 99) l2 = 99;
            const float4 a = av[l2];
            const float4 w = w3p[i];
            m = fmaxf(m, fmaxf(fmaxf(a.x + w.x, a.y + w.y),
                               fmaxf(a.z + w.z, a.w + w.w)));
        }
        m = dppmax<QX1>(m);
        m = dppmax<QX2>(m);
        m = dppmax<SHL4>(m);
        if (q == 0) s_a3[o] = fmaxf(m - 1.0f, 0.0f);
    }
    bar_lds();

    // ---- Phase F: dense [120]->[84] + tanh; 8 threads/output; DPP sum-tree
    if (tid < 672) {
        const int o = tid >> 3, q = tid & 7;
        float acc = 0.0f;
        #pragma unroll
        for (int i = 0; i < 15; ++i)
            acc = fmaf(s_a3[q * 15 + i], wdp[i], acc);
        acc = dppadd<QX1>(acc);
        acc = dppadd<QX2>(acc);
        acc = dppadd<SHL4>(acc);
        if (q == 0)
            s_a4[o] = 1.0f - 2.0f / (__expf(2.0f * acc) + 1.0f);  // tanh
    }
    bar_lds();

    // ---- Phase G: fc [84]->[10] + bias + log_softmax, single wave, LDS-only
    if (tid < 64) {
        float acc = 0.0f;
        if (tid < 40) {
            const int o = tid >> 2, q = tid & 3;
            #pragma unroll 7
            for (int i = 0; i < 21; ++i) {
                const int k = q * 21 + i;
                acc = fmaf(s_a4[k], s_wf[k * 10 + o], acc);
            }
            acc += __shfl_xor(acc, 1);
            acc += __shfl_xor(acc, 2);
            acc += s_wf[840 + o];
        }
        const float lg = __shfl(acc, (tid < 10) ? tid * 4 : 0);
        if (tid < 16) {
            float v = (tid < 10) ? lg : -1e30f;
            #pragma unroll
            for (int d = 1; d < 16; d <<= 1)
                v = fmaxf(v, __shfl_xor(v, d));
            float e = (tid < 10) ? __expf(lg - v) : 0.0f;
            float ssum = e;
            #pragma unroll
            for (int d = 1; d < 16; d <<= 1)
                ssum += __shfl_xor(ssum, d);
            if (tid < 10)
                out[img * 10 + tid] = lg - v - __logf(ssum);
        }
    }
}

extern "C" void kernel_launch(void* const* d_in, const int* in_sizes, int n_in,
                              void* d_out, int out_size, void* d_ws, size_t ws_size,
                              hipStream_t stream) {
    const float* x   = (const float*)d_in[0];
    const float* w1  = (const float*)d_in[1];
    const float* w2  = (const float*)d_in[2];
    const float* w3  = (const float*)d_in[3];
    const float* wd  = (const float*)d_in[4];
    const float* wf  = (const float*)d_in[5];
    const float* bfv = (const float*)d_in[6];
    float* out = (float*)d_out;

    const int B = in_sizes[0] / (3 * 32 * 32);
    fused_lenet<<<dim3(B), dim3(NT), 0, stream>>>(
        x, w1, w2, w3, wd, wf, bfv, out);
}

// Round 4
// 73.530 us; speedup vs baseline: 1.2803x; 1.2803x over previous
//
#include <hip/hip_runtime.h>
#include <math.h>

// Fuzzy LeNet-5, Yager p=1 == Lukasiewicz: T(a,b)=max(0,a+b-1).
// Fuzzy conv == max-plus conv: out = relu(max_{c,kh,kw}(x+w) - 1).
// maxpool2 folds into the conv via dilated 6x6 weights:
//   W'[uy][ux] = max_{dy,dx in {0,1}, uy-dy,ux-dx in [0,5)} w[uy-dy][ux-dx]
//
// R17: REVERT to the proven-best configuration (73.6 us). Session evidence:
//  - R14 (conv1 u-split across 16 waves, DPP h-combine): +16 us.
//  - R15 (lgkmcnt-only barriers + max3 trees, layout untouched): neutral.
//  - R16 (zero LDS atomics, DPP lane-group reduction): +20 us.
// Conclusion: the R13 task layout + LDS-atomicMax combine is a sharp local
// optimum; both structural re-mappings regressed heavily and local pipe
// tweaks are flat. Remaining measured time is dominated by harness-side
// costs (268 MB workspace-poison fill ~41 us at 82% HBM peak + reset
// dispatch overhead); the kernel's attackable budget is a few us and flat.
// Channel/h-partials combined via LDS atomicMax on relu'd float bits
// (exact: relu>=0 floats order as uints; relu(max-1)=max(relu(p-1))).

#define NT 1024
#define ROWS 34                 // padded image row stride
#define PLANE (32 * ROWS)       // 1088

__device__ __forceinline__ void dilate_row(const float* __restrict__ raw,
                                           int r, float* __restrict__ dst) {
    // dst[0..5] = max over kh in {r-1,r} cap [0,4], kw in {col-1,col} cap [0,4]
    const int rA = (r > 0) ? r - 1 : 0;
    const int rB = (r < 5) ? r : 4;
    float t0 = fmaxf(raw[rA * 5 + 0], raw[rB * 5 + 0]);
    float t1 = fmaxf(raw[rA * 5 + 1], raw[rB * 5 + 1]);
    float t2 = fmaxf(raw[rA * 5 + 2], raw[rB * 5 + 2]);
    float t3 = fmaxf(raw[rA * 5 + 3], raw[rB * 5 + 3]);
    float t4 = fmaxf(raw[rA * 5 + 4], raw[rB * 5 + 4]);
    float2* d = (float2*)dst;
    d[0] = make_float2(t0, fmaxf(t0, t1));
    d[1] = make_float2(fmaxf(t1, t2), fmaxf(t2, t3));
    d[2] = make_float2(fmaxf(t3, t4), t4);
}

__global__ __launch_bounds__(NT) void fused_lenet(
    const float* __restrict__ x,   // [B,3,32,32]
    const float* __restrict__ w1,  // [6,3,5,5]
    const float* __restrict__ w2,  // [16,6,5,5]
    const float* __restrict__ w3,  // [120,16,5,5]
    const float* __restrict__ wd,  // [120,84]
    const float* __restrict__ wf,  // [84,10]
    const float* __restrict__ bfv, // [10]
    float* __restrict__ out)       // [B,10]
{
    const int img = blockIdx.x;
    const int tid = threadIdx.x;

    __shared__ float s_in[3 * PLANE];          // 13056 B
    __shared__ float s_w1d[648];               // [oc][c][uy][6]
    __shared__ float s_w2d[3456];              // [oc][c][uy][6]
    __shared__ float s_wf[850];                // wf[840] + bf[10]
    __shared__ unsigned s_a1u[1176];           // conv1 out, relu'd float bits
    __shared__ unsigned s_a2u[400];            // conv2 out, relu'd float bits
    __shared__ float s_a3[120];
    __shared__ float s_a4[84];

    float4 w3p[13];   // filled after conv1 body, consumed in phase E

    // ---- Phase A: stage image + wf/bf + zero accums + dilate w1 AND w2
    //      (both dilations read global directly; latency hides under staging)
    {
        const float2* src = (const float2*)(x + img * 3072);
        for (int i = tid; i < 1536; i += NT) {
            const int c = i >> 9, rem = i & 511, r = rem >> 4, col2 = rem & 15;
            ((float2*)s_in)[c * (PLANE / 2) + r * (ROWS / 2) + col2] = src[i];
        }
        if (tid < 420) ((float2*)s_wf)[tid] = ((const float2*)wf)[tid];
        if (tid >= 428 && tid < 438) s_wf[840 + tid - 428] = bfv[tid - 428];
        for (int i = tid; i < 1176; i += NT) s_a1u[i] = 0u;
        if (tid < 400) s_a2u[tid] = 0u;
        if (tid >= 320 && tid < 428) {          // w1 dilation: 108 row-tasks
            const int e = tid - 320;
            const int occ = e / 6, r = e - occ * 6;   // occ = oc*3+c
            dilate_row(w1 + occ * 25, r, s_w1d + occ * 36 + r * 6);
        }
        if (tid >= 448) {                       // w2 dilation: 576 row-tasks
            const int e = tid - 448;
            const int occ = e / 6, r = e - occ * 6;   // occ = oc*6+c
            dilate_row(w2 + occ * 25, r, s_w2d + occ * 36 + r * 6);
        }
    }
    __syncthreads();

    // ---- Phase C: conv1 partials; 336 tasks (c,ocg,py,s,h), 3 oc per task,
    //      3 uy x 7-px strip, x row loaded once per uy and reused across oc
    if (tid < 336) {
        const int c = tid / 112;
        const int r = tid - c * 112;
        const int ocg = r / 56;
        const int r2 = r - ocg * 56;
        const int py = r2 >> 2;
        const int s = (r2 >> 1) & 1;
        const int h = r2 & 1;
        float acc[3][7];
        #pragma unroll
        for (int o = 0; o < 3; ++o)
            #pragma unroll
            for (int j = 0; j < 7; ++j) acc[o][j] = -1e30f;
        const float* xbase = s_in + c * PLANE + (2 * py + 3 * h) * ROWS + 14 * s;
        #pragma unroll
        for (int u = 0; u < 3; ++u) {
            float xv[18];
            #pragma unroll
            for (int i2 = 0; i2 < 9; ++i2)
                ((float2*)xv)[i2] = ((const float2*)(xbase + u * ROWS))[i2];
            #pragma unroll
            for (int o = 0; o < 3; ++o) {
                const float* wbase =
                    s_w1d + ((ocg * 3 + o) * 3 + c) * 36 + h * 18 + u * 6;
                float wv[6];
                #pragma unroll
                for (int i2 = 0; i2 < 3; ++i2)
                    ((float2*)wv)[i2] = ((const float2*)wbase)[i2];
                #pragma unroll
                for (int j = 0; j < 7; ++j) {
                    #pragma unroll
                    for (int ux = 0; ux < 6; ++ux)
                        acc[o][j] = fmaxf(acc[o][j], xv[2 * j + ux] + wv[ux]);
                }
            }
        }
        #pragma unroll
        for (int o = 0; o < 3; ++o) {
            const int obase = (ocg * 3 + o) * 196 + py * 14 + 7 * s;
            #pragma unroll
            for (int j = 0; j < 7; ++j) {
                const float rl = fmaxf(acc[o][j] - 1.0f, 0.0f);
                atomicMax(&s_a1u[obase + j], __float_as_uint(rl));
            }
        }
    }
    // prefetch w3 into registers (in flight through conv2 + barriers, used E)
    if (tid < 960) {
        const int o = tid >> 3, q = tid & 7;
        const float4* wv = (const float4*)(w3 + o * 400);
        #pragma unroll
        for (int i = 0; i < 13; ++i) {
            int l = q + 8 * i; if (l > 99) l = 99;
            w3p[i] = wv[l];
        }
    }
    __syncthreads();

    // ---- Phase D: conv2 partials; 240 tasks (ocq,py,c,h), 4 oc per task,
    //      3 uy x 5-px row, x row loaded once per uy and reused across oc
    if (tid < 240) {
        const int ocq = tid / 60;
        const int r = tid - ocq * 60;
        const int py = r / 12;
        const int r2 = r - py * 12;
        const int c = r2 >> 1;
        const int h = r2 & 1;
        float acc[4][5];
        #pragma unroll
        for (int o = 0; o < 4; ++o)
            #pragma unroll
            for (int j = 0; j < 5; ++j) acc[o][j] = -1e30f;
        const float* a1f = (const float*)s_a1u;
        const float* xbase = a1f + c * 196 + (2 * py + 3 * h) * 14;
        #pragma unroll
        for (int u = 0; u < 3; ++u) {
            float xv[14];
            #pragma unroll
            for (int i2 = 0; i2 < 7; ++i2)
                ((float2*)xv)[i2] = ((const float2*)(xbase + u * 14))[i2];
            #pragma unroll
            for (int o = 0; o < 4; ++o) {
                const float* wbase =
                    s_w2d + ((ocq * 4 + o) * 6 + c) * 36 + h * 18 + u * 6;
                float wv[6];
                #pragma unroll
                for (int i2 = 0; i2 < 3; ++i2)
                    ((float2*)wv)[i2] = ((const float2*)wbase)[i2];
                #pragma unroll
                for (int j = 0; j < 5; ++j) {
                    #pragma unroll
                    for (int ux = 0; ux < 6; ++ux)
                        acc[o][j] = fmaxf(acc[o][j], xv[2 * j + ux] + wv[ux]);
                }
            }
        }
        #pragma unroll
        for (int o = 0; o < 4; ++o) {
            const int obase = (ocq * 4 + o) * 25 + py * 5;
            #pragma unroll
            for (int j = 0; j < 5; ++j) {
                const float rl = fmaxf(acc[o][j] - 1.0f, 0.0f);
                atomicMax(&s_a2u[obase + j], __float_as_uint(rl));
            }
        }
    }
    // prefetch wd for the dense phase (in flight during E)
    float wdp[15];
    if (tid < 672) {
        const int o = tid >> 3, q = tid & 7;
        #pragma unroll
        for (int i = 0; i < 15; ++i)
            wdp[i] = wd[(q * 15 + i) * 84 + o];
    }
    __syncthreads();

    // ---- Phase E: L3 [16,5,5]->[120]; 8 threads/output, prefetched w3
    if (tid < 960) {
        const int o = tid >> 3, q = tid & 7;
        const float4* av = (const float4*)(const float*)s_a2u;
        float m = -1e30f;
        #pragma unroll
        for (int i = 0; i < 13; ++i) {
            int l = q + 8 * i; if (l > 99) l = 99;
            const float4 a = av[l];
            const float4 w = w3p[i];
            m = fmaxf(m, fmaxf(fmaxf(a.x + w.x, a.y + w.y),
                               fmaxf(a.z + w.z, a.w + w.w)));
        }
        m = fmaxf(m, __shfl_xor(m, 1));
        m = fmaxf(m, __shfl_xor(m, 2));
        m = fmaxf(m, __shfl_xor(m, 4));
        if (q == 0) s_a3[o] = fmaxf(m - 1.0f, 0.0f);
    }
    __syncthreads();

    // ---- Phase F: dense [120]->[84] + tanh; 8 threads/output, prefetched wd
    if (tid < 672) {
        const int o = tid >> 3, q = tid & 7;
        float acc = 0.0f;
        #pragma unroll
        for (int i = 0; i < 15; ++i)
            acc = fmaf(s_a3[q * 15 + i], wdp[i], acc);
        acc += __shfl_xor(acc, 1);
        acc += __shfl_xor(acc, 2);
        acc += __shfl_xor(acc, 4);
        if (q == 0)
            s_a4[o] = 1.0f - 2.0f / (__expf(2.0f * acc) + 1.0f);  // tanh
    }
    __syncthreads();

    // ---- Phase G: fc [84]->[10] + bias + log_softmax, single wave, LDS-only
    if (tid < 64) {
        float acc = 0.0f;
        if (tid < 40) {
            const int o = tid >> 2, q = tid & 3;
            #pragma unroll 7
            for (int i = 0; i < 21; ++i) {
                const int k = q * 21 + i;
                acc = fmaf(s_a4[k], s_wf[k * 10 + o], acc);
            }
            acc += __shfl_xor(acc, 1);
            acc += __shfl_xor(acc, 2);
            acc += s_wf[840 + o];
        }
        const float lg = __shfl(acc, (tid < 10) ? tid * 4 : 0);
        if (tid < 16) {
            float v = (tid < 10) ? lg : -1e30f;
            #pragma unroll
            for (int d = 1; d < 16; d <<= 1)
                v = fmaxf(v, __shfl_xor(v, d));
            float e = (tid < 10) ? __expf(lg - v) : 0.0f;
            float ssum = e;
            #pragma unroll
            for (int d = 1; d < 16; d <<= 1)
                ssum += __shfl_xor(ssum, d);
            if (tid < 10)
                out[img * 10 + tid] = lg - v - __logf(ssum);
        }
    }
}

extern "C" void kernel_launch(void* const* d_in, const int* in_sizes, int n_in,
                              void* d_out, int out_size, void* d_ws, size_t ws_size,
                              hipStream_t stream) {
    const float* x   = (const float*)d_in[0];
    const float* w1  = (const float*)d_in[1];
    const float* w2  = (const float*)d_in[2];
    const float* w3  = (const float*)d_in[3];
    const float* wd  = (const float*)d_in[4];
    const float* wf  = (const float*)d_in[5];
    const float* bfv = (const float*)d_in[6];
    float* out = (float*)d_out;

    const int B = in_sizes[0] / (3 * 32 * 32);
    fused_lenet<<<dim3(B), dim3(NT), 0, stream>>>(
        x, w1, w2, w3, wd, wf, bfv, out);
}